// Round 4
// baseline (331.143 us; speedup 1.0000x reference)
//
#include <hip/hip_runtime.h>

// Problem constants (from reference setup_inputs): B=8, S=2048, H=1024
#define BB 8
#define SS 2048
#define HH 1024

// ---------------------------------------------------------------------------
// Kernel 1: per-token phase (round-0 proven version, bit-identical math).
// One wave (64 lanes) per token; block = 4 waves. Computes start/end logits
// (4 dots of length H), candidacy, scores. Emits ss[token] = start_cand ?
// score_s : -1e30 sentinel (same for se/end) so the pair kernel needs no
// boolean arrays. fp64 accumulation: the pair>0 / sl0<=sl1 sign thresholds
// are hard cutoffs; stay as close to the fp64 numpy reference as possible.
// ---------------------------------------------------------------------------
__global__ __launch_bounds__(256) void token_kernel(
    const float* __restrict__ rep, const int* __restrict__ mask,
    const float* __restrict__ Ws, const float* __restrict__ bs,
    const float* __restrict__ We, const float* __restrict__ be,
    const float* __restrict__ Wm, const float* __restrict__ bm,
    float* __restrict__ ss, float* __restrict__ se)
{
    const int token = blockIdx.x * 4 + (threadIdx.x >> 6);
    const int lane  = threadIdx.x & 63;
    const float* r = rep + (size_t)token * HH;

    double a0 = 0.0, a1 = 0.0, a2 = 0.0, a3 = 0.0;
    #pragma unroll
    for (int k = 0; k < HH / 256; ++k) {
        const int h = k * 256 + lane * 4;           // 4 consecutive features
        const float4 rv = *(const float4*)(r + h);
        // Ws/We are (H,2) row-major: [h][0],[h][1] interleaved
        const float4 w0 = *(const float4*)(Ws + 2 * h);      // h, h+1
        const float4 w1 = *(const float4*)(Ws + 2 * h + 4);  // h+2, h+3
        const float4 e0 = *(const float4*)(We + 2 * h);
        const float4 e1 = *(const float4*)(We + 2 * h + 4);
        a0 += (double)rv.x * w0.x + (double)rv.y * w0.z + (double)rv.z * w1.x + (double)rv.w * w1.z;
        a1 += (double)rv.x * w0.y + (double)rv.y * w0.w + (double)rv.z * w1.y + (double)rv.w * w1.w;
        a2 += (double)rv.x * e0.x + (double)rv.y * e0.z + (double)rv.z * e1.x + (double)rv.w * e1.z;
        a3 += (double)rv.x * e0.y + (double)rv.y * e0.w + (double)rv.z * e1.y + (double)rv.w * e1.w;
    }
    // wave-64 butterfly reduce (4 accumulators)
    #pragma unroll
    for (int off = 32; off >= 1; off >>= 1) {
        a0 += __shfl_down(a0, off);
        a1 += __shfl_down(a1, off);
        a2 += __shfl_down(a2, off);
        a3 += __shfl_down(a3, off);
    }
    if (lane == 0) {
        const double sl0 = a0 + (double)bs[0];
        const double sl1 = a1 + (double)bs[1];
        const double el0 = a2 + (double)be[0];
        const double el1 = a3 + (double)be[1];
        const bool m  = (mask[token] != 0);
        const bool sc = m && (sl0 <= sl1);
        const bool ec = m && (el0 <= el1);
        const double sv = sl0 * (double)Wm[0] + sl1 * (double)Wm[1];
        const double ev = el0 * (double)Wm[2] + el1 * (double)Wm[3];
        ss[token] = sc ? (float)sv : -1e30f;   // sentinel: pair>0 impossible
        se[token] = ec ? (float)ev : -1e30f;
    }
}

// ---------------------------------------------------------------------------
// Kernel 2: pair phase. Pure store-bound: 268 MB of writes.
// PERSISTENT + WAVE-CONTIGUOUS (the untested cell of round-1/round-3 matrix):
//  - 2048 blocks (8/CU exactly), each owns 8 consecutive rows of one batch
//    (2048 % 8 == 0, so b is constant per block).
//  - Thread t owns j = t*4 and j = 1024 + t*4: lane-stride is 16 B, so every
//    dwordx4 store instruction covers 1 KB of consecutive addresses (the
//    round-2 lesson: NEVER break this).
//  - se slice loaded ONCE per thread, reused across all 8 rows (8x fewer
//    reads and no per-block setup churn); regular L2-routed stores (the
//    6.5 TB/s fill-kernel path), 32 stores per thread lifetime for deep
//    store pipelining.
// ---------------------------------------------------------------------------
__global__ __launch_bounds__(256) void pair_kernel(
    const float* __restrict__ ss, const float* __restrict__ se,
    const float* __restrict__ bm,
    float* __restrict__ out_valid, float* __restrict__ out_score)
{
    const int row0 = blockIdx.x * 8;       // 8 rows per block, same batch
    const int b    = row0 >> 11;
    const int jA   = threadIdx.x * 4;      // first j slice (wave-contiguous)
    const int jB   = 1024 + jA;            // second j slice
    const float bmv = bm[0];

    const float* seb = se + b * SS;
    const float4 eA = *(const float4*)(seb + jA);   // reused for all 8 rows
    const float4 eB = *(const float4*)(seb + jB);

    #pragma unroll
    for (int r = 0; r < 8; ++r) {
        const int row = row0 + r;
        const int i   = row & (SS - 1);
        const float s_i = ss[row];         // uniform -> scalar load
        const size_t rowoff = (size_t)row * SS;

        // ---- half A: j = jA ----
        {
            // match reference add order: (score_s + score_e) + bm
            const float p0 = (s_i + eA.x) + bmv;
            const float p1 = (s_i + eA.y) + bmv;
            const float p2 = (s_i + eA.z) + bmv;
            const float p3 = (s_i + eA.w) + bmv;
            const bool v0 = (i <= jA    ) && (p0 > 0.0f);
            const bool v1 = (i <= jA + 1) && (p1 > 0.0f);
            const bool v2 = (i <= jA + 2) && (p2 > 0.0f);
            const bool v3 = (i <= jA + 3) && (p3 > 0.0f);
            const float4 vv = make_float4(v0 ? 1.0f : 0.0f, v1 ? 1.0f : 0.0f,
                                          v2 ? 1.0f : 0.0f, v3 ? 1.0f : 0.0f);
            const float4 pv = make_float4(v0 ? p0 : 0.0f, v1 ? p1 : 0.0f,
                                          v2 ? p2 : 0.0f, v3 ? p3 : 0.0f);
            *(float4*)(out_valid + rowoff + jA) = vv;
            *(float4*)(out_score + rowoff + jA) = pv;
        }
        // ---- half B: j = jB ----
        {
            const float p0 = (s_i + eB.x) + bmv;
            const float p1 = (s_i + eB.y) + bmv;
            const float p2 = (s_i + eB.z) + bmv;
            const float p3 = (s_i + eB.w) + bmv;
            const bool v0 = (i <= jB    ) && (p0 > 0.0f);
            const bool v1 = (i <= jB + 1) && (p1 > 0.0f);
            const bool v2 = (i <= jB + 2) && (p2 > 0.0f);
            const bool v3 = (i <= jB + 3) && (p3 > 0.0f);
            const float4 vv = make_float4(v0 ? 1.0f : 0.0f, v1 ? 1.0f : 0.0f,
                                          v2 ? 1.0f : 0.0f, v3 ? 1.0f : 0.0f);
            const float4 pv = make_float4(v0 ? p0 : 0.0f, v1 ? p1 : 0.0f,
                                          v2 ? p2 : 0.0f, v3 ? p3 : 0.0f);
            *(float4*)(out_valid + rowoff + jB) = vv;
            *(float4*)(out_score + rowoff + jB) = pv;
        }
    }
}

extern "C" void kernel_launch(void* const* d_in, const int* in_sizes, int n_in,
                              void* d_out, int out_size, void* d_ws, size_t ws_size,
                              hipStream_t stream) {
    const float* rep  = (const float*)d_in[0];
    const int*   mask = (const int*)  d_in[1];
    const float* Ws   = (const float*)d_in[2];
    const float* bs   = (const float*)d_in[3];
    const float* We   = (const float*)d_in[4];
    const float* be   = (const float*)d_in[5];
    const float* Wm   = (const float*)d_in[6];
    const float* bm   = (const float*)d_in[7];

    float* ss = (float*)d_ws;            // B*S floats
    float* se = ss + BB * SS;            // B*S floats (total 128 KB of ws)

    float* out_valid = (float*)d_out;                          // B*S*S floats
    float* out_score = out_valid + (size_t)BB * SS * SS;       // B*S*S floats

    // Phase 1: 16384 tokens, 1 wave each, 4 waves/block -> 4096 blocks
    token_kernel<<<BB * SS / 4, 256, 0, stream>>>(rep, mask, Ws, bs, We, be,
                                                  Wm, bm, ss, se);

    // Phase 2: 16384 rows, 8 rows/block -> 2048 blocks x 256 threads
    pair_kernel<<<BB * SS / 8, 256, 0, stream>>>(ss, se, bm,
                                                 out_valid, out_score);
}